// Round 1
// baseline (405.909 us; speedup 1.0000x reference)
//
#include <hip/hip_runtime.h>

// Causal self-attention. fp32 in/out, bf16 MFMA compute inside.
// R8: QKV GEMM ported to the 256x256 8-phase counted-vmcnt template
// (T3+T4+T5 per guide §5.5): BK=64, 8 waves (2Mx4N), LDS 128KB as
// [buf][ks][256][32] K-half panels (64B rows -> bank-parity spread, b128
// reads at BW floor with LINEAR lds => global_load_lds staging stays legal).
// Stage schedule: phase p of tile t stages {t+1:A-ks1, t+1:B-ks1, t+2:A-ks0,
// t+2:B-ks0}; boundary wait is vmcnt(4) (2 units in flight), vmcnt(0) only
// entering the last tile. Flash attn + out-GEMM (m97 128^2) unchanged from R7.
// MFMA 16x16x32 bf16 layouts (guide m89/m91):
//   A[m=lane&15][k=quad*8+j], B[k=quad*8+j][n=lane&15], C/D: row=quad*4+r, col=lane&15

typedef unsigned short ushort;
typedef __attribute__((ext_vector_type(8))) short short8;
typedef __attribute__((ext_vector_type(4))) float floatx4;

#define T_SEQ 2048
#define NQKV  6144
#define DMODEL 2048
#define HDIM  128
#define NEG_BIG (-3.0e38f)

#define WAITVM(n) asm volatile("s_waitcnt vmcnt(" #n ")" ::: "memory")
#define WAITLGKM0 asm volatile("s_waitcnt lgkmcnt(0)" ::: "memory")

__device__ __forceinline__ ushort f2bf(float f) {
  unsigned u = __float_as_uint(f);
  u += 0x7fffu + ((u >> 16) & 1u);   // RNE
  return (ushort)(u >> 16);
}
__device__ __forceinline__ void stout(ushort* p, float v) { *p = f2bf(v); }
__device__ __forceinline__ void stout(float* p, float v)  { *p = v; }

__device__ __forceinline__ void gload_lds16(const ushort* g, ushort* l) {
  __builtin_amdgcn_global_load_lds(
      (const __attribute__((address_space(1))) void*)g,
      (__attribute__((address_space(3))) void*)l,
      16, 0, 0);
}

// ---- fp32 [R x C] (row stride ld_in) -> dense bf16 [R x C] ----
__global__ void cvt2d(const float* __restrict__ in, ushort* __restrict__ out,
                      int R, int C, int ld_in) {
  int idx = blockIdx.x * blockDim.x + threadIdx.x;
  int c4 = C >> 2;
  if (idx >= R * c4) return;
  int r = idx / c4, c = (idx - r * c4) * 4;
  float4 v = *(const float4*)(in + (size_t)r * ld_in + c);
  ushort4 o;
  o.x = f2bf(v.x); o.y = f2bf(v.y); o.z = f2bf(v.z); o.w = f2bf(v.w);
  *(ushort4*)(out + (size_t)r * C + c) = o;
}

// ---- fp32 in[R][C] (row stride ld_in) -> bf16 out[C][R] dense ----
__global__ void cvt2dT(const float* __restrict__ in, ushort* __restrict__ out,
                       int R, int C, int ld_in) {
  __shared__ float tile[32][33];
  int c0 = blockIdx.x * 32, r0 = blockIdx.y * 32;
  int tx = threadIdx.x, ty = threadIdx.y;  // 32 x 8
#pragma unroll
  for (int q = 0; q < 4; q++)
    tile[ty + q * 8][tx] = in[(size_t)(r0 + ty + q * 8) * ld_in + c0 + tx];
  __syncthreads();
#pragma unroll
  for (int q = 0; q < 4; q++)
    out[(size_t)(c0 + ty + q * 8) * R + r0 + tx] = f2bf(tile[tx][ty + q * 8]);
}

// ---- C[M,N] = A[M,K] @ Bt[N,K]^T, bf16 in, OutT out (m97 structure) ----
template <typename OutT>
__global__ void gemm_bt(
    const ushort* __restrict__ A, const ushort* __restrict__ Bt,
    OutT* __restrict__ C, int M, int N, int K, int ldc) {
  __shared__ ushort sA[128 * 32];
  __shared__ ushort sB[128 * 32];
  const int tid = threadIdx.x;
  const int w = tid >> 6, l = tid & 63;
  const int quad = l >> 4, l16 = l & 15;
  const int row0 = blockIdx.x * 128, col0 = blockIdx.y * 128;
  const int wm = (w >> 1) * 64, wn = (w & 1) * 64;

  floatx4 acc[4][4];
  const floatx4 zero = {0.f, 0.f, 0.f, 0.f};
#pragma unroll
  for (int i = 0; i < 4; i++)
#pragma unroll
    for (int j = 0; j < 4; j++) acc[i][j] = zero;

  const int srow = w * 16 + (l >> 2);
  const int scol = (l & 3) * 8;
  const ushort* gA = A + (size_t)(row0 + srow) * K + scol;
  const ushort* gB = Bt + (size_t)(col0 + srow) * K + scol;
  ushort* lA = &sA[(w * 16) * 32];
  ushort* lB = &sB[(w * 16) * 32];

  for (int k0 = 0; k0 < K; k0 += 32) {
    __syncthreads();
    gload_lds16(gA + k0, lA);
    gload_lds16(gA + k0 + (size_t)64 * K, lA + 64 * 32);
    gload_lds16(gB + k0, lB);
    gload_lds16(gB + k0 + (size_t)64 * K, lB + 64 * 32);
    __syncthreads();
    short8 af[4], bfr[4];
#pragma unroll
    for (int i = 0; i < 4; i++)
      af[i] = *(const short8*)&sA[(wm + i * 16 + l16) * 32 + quad * 8];
#pragma unroll
    for (int j = 0; j < 4; j++)
      bfr[j] = *(const short8*)&sB[(wn + j * 16 + l16) * 32 + quad * 8];
#pragma unroll
    for (int i = 0; i < 4; i++)
#pragma unroll
      for (int j = 0; j < 4; j++)
        acc[i][j] = __builtin_amdgcn_mfma_f32_16x16x32_bf16(af[i], bfr[j], acc[i][j], 0, 0, 0);
  }

#pragma unroll
  for (int i = 0; i < 4; i++)
#pragma unroll
    for (int j = 0; j < 4; j++) {
      int r0 = row0 + wm + i * 16 + quad * 4;
      int c = col0 + wn + j * 16 + l16;
#pragma unroll
      for (int r = 0; r < 4; r++)
        stout(&C[(size_t)(r0 + r) * ldc + c], acc[i][j][r]);
    }
}

// ---- C[M,N] = A[M,K] @ Bt[N,K]^T, bf16 in, 256^2 8-phase pipeline ----
// 512 threads = 8 waves (2M x 4N); per-wave C = 128x64 (8 m-frags x 4 n-frags).
// LDS per operand: [2 buf][2 ks][256 rows][32 k] bf16 (64KB); total 128KB.
// Per tile t (buf=t&1), 4 phases (ks,ch): P0=(0,0) P1=(0,1) P2=(1,0) P3=(1,1).
// Phase stages one 16KB unit (2 x global_load_lds dwordx4 per thread):
//   P0: t+1 A-ks1 (other buf)   P1: t+1 B-ks1 (other buf)
//   P2: t+2 A-ks0 (this buf; last reader was P1)   P3: t+2 B-ks0 (ditto)
// Boundary wait at P3: vmcnt(4) -> tile t+1 fully landed, 2 units in flight.
template <typename OutT>
__global__ __launch_bounds__(512, 2) void gemm_bt_256(
    const ushort* __restrict__ A, const ushort* __restrict__ Bt,
    OutT* __restrict__ C, int M, int N, int K, int ldc) {
  __shared__ ushort sA[2][2][256 * 32];
  __shared__ ushort sB[2][2][256 * 32];
  const int tid = threadIdx.x;
  const int wid = tid >> 6, l = tid & 63;
  const int quad = l >> 4, l16 = l & 15;
  const int wr = wid >> 2, wc = wid & 3;
  const int row0 = blockIdx.x * 256, col0 = blockIdx.y * 256;
  const int NT = K >> 6;

  floatx4 acc[8][4];
  const floatx4 zero = {0.f, 0.f, 0.f, 0.f};
#pragma unroll
  for (int i = 0; i < 8; i++)
#pragma unroll
    for (int j = 0; j < 4; j++) acc[i][j] = zero;

  // staging: wave wid covers rows [wid*32, wid*32+32); lane l -> row +(l>>2),
  // k-bytes (l&3)*16 within the 32-wide (64B) K-half panel. LDS dest linear.
  const ushort* gA = A + (size_t)(row0 + wid * 32 + (l >> 2)) * K + (l & 3) * 8;
  const ushort* gB = Bt + (size_t)(col0 + wid * 32 + (l >> 2)) * K + (l & 3) * 8;

  auto stageA = [&](int tt, int ks) {
    ushort* dst = &sA[tt & 1][ks][(wid * 32) * 32];
    const ushort* g = gA + (size_t)tt * 64 + ks * 32;
    gload_lds16(g, dst);
    gload_lds16(g + (size_t)16 * K, dst + 16 * 32);
  };
  auto stageB = [&](int tt, int ks) {
    ushort* dst = &sB[tt & 1][ks][(wid * 32) * 32];
    const ushort* g = gB + (size_t)tt * 64 + ks * 32;
    gload_lds16(g, dst);
    gload_lds16(g + (size_t)16 * K, dst + 16 * 32);
  };

  // prologue: tile0 all 4 units + tile1 ks0 units -> vmcnt(4) leaves tile1's
  // 2 units in flight, tile0 fully landed.
  stageA(0, 0); stageB(0, 0); stageA(0, 1); stageB(0, 1);
  if (NT > 1) {
    stageA(1, 0); stageB(1, 0);
    WAITVM(4);
  } else {
    WAITVM(0);
  }
  __builtin_amdgcn_s_barrier();

#define PHASE(ks, ch, STAGE_STMT, VM_TAIL)                                    \
  {                                                                           \
    if ((ch) == 0) {                                                          \
      _Pragma("unroll")                                                       \
      for (int j = 0; j < 4; j++)                                             \
        bfr[j] = *(const short8*)&sB[buf][ks][(wc * 64 + j * 16 + l16) * 32 + quad * 8]; \
    }                                                                         \
    _Pragma("unroll")                                                         \
    for (int i = 0; i < 4; i++)                                               \
      af[i] = *(const short8*)&sA[buf][ks][(wr * 128 + ((ch) * 4 + i) * 16 + l16) * 32 + quad * 8]; \
    STAGE_STMT;                                                               \
    __builtin_amdgcn_s_barrier();                                             \
    WAITLGKM0;                                                                \
    __builtin_amdgcn_s_setprio(1);                                            \
    _Pragma("unroll")                                                         \
    for (int i = 0; i < 4; i++)                                               \
      _Pragma("unroll")                                                       \
      for (int j = 0; j < 4; j++)                                             \
        acc[(ch) * 4 + i][j] = __builtin_amdgcn_mfma_f32_16x16x32_bf16(       \
            af[i], bfr[j], acc[(ch) * 4 + i][j], 0, 0, 0);                    \
    __builtin_amdgcn_s_setprio(0);                                            \
    VM_TAIL;                                                                  \
    __builtin_amdgcn_s_barrier();                                             \
  }

  for (int t = 0; t < NT; ++t) {
    const int buf = t & 1;
    short8 af[4], bfr[4];
    PHASE(0, 0, if (t + 1 < NT) stageA(t + 1, 1), );
    PHASE(0, 1, if (t + 1 < NT) stageB(t + 1, 1), );
    PHASE(1, 0, if (t + 2 < NT) stageA(t + 2, 0), );
    PHASE(1, 1, if (t + 2 < NT) stageB(t + 2, 0),
          if (t < NT - 2) { WAITVM(4); } else if (t == NT - 2) { WAITVM(0); });
  }
#undef PHASE

#pragma unroll
  for (int mi = 0; mi < 8; mi++)
#pragma unroll
    for (int j = 0; j < 4; j++) {
      int r0 = row0 + wr * 128 + mi * 16 + quad * 4;
      int c = col0 + wc * 64 + j * 16 + l16;
#pragma unroll
      for (int r = 0; r < 4; r++)
        stout(&C[(size_t)(r0 + r) * ldc + c], acc[mi][j][r]);
    }
}

// ---- flash attention (causal): one 64-row q-tile per block; grid (bh, qtOrd) ----
// sK: 2 buffers, 16 groups each; group = 4 rows x 128 ushort + 16-ushort pad
// (528 ushort stride). DMA writes one group per instruction (1024B contig);
// the pad staggers groups by 8 banks -> K-fragment b128 reads are 4-way.
__global__ __launch_bounds__(256, 2) void flash_attn(
    const ushort* __restrict__ qkv, ushort* __restrict__ attn) {
  __shared__ ushort sK[2][16 * 528];
  __shared__ ushort sVt[128 * 72];   // swizzled [hd][t]
  __shared__ ushort sP[4 * 16 * 72]; // per-wave P, stride 72

  const int tid = threadIdx.x;
  const int w = tid >> 6, l = tid & 63;
  const int quad = l >> 4, l16 = l & 15;
  const int bh = blockIdx.x;            // bh-major: same-bh blocks share an XCD
  const int qt = 31 - (int)blockIdx.y;  // biggest blocks dispatch first
  const int b = bh >> 4, h = bh & 15;
  const size_t rowbase = (size_t)b * T_SEQ;

  short8 qf[4];
  {
    const ushort* qp = qkv + (rowbase + qt * 64 + w * 16 + l16) * NQKV + h * HDIM + quad * 8;
#pragma unroll
    for (int s = 0; s < 4; s++) qf[s] = *(const short8*)(qp + s * 32);
  }
  floatx4 o[8];
  const floatx4 zero = {0.f, 0.f, 0.f, 0.f};
#pragma unroll
  for (int n = 0; n < 8; n++) o[n] = zero;
  float m_i[4], l_i[4];
#pragma unroll
  for (int r = 0; r < 4; r++) { m_i[r] = NEG_BIG; l_i[r] = 0.f; }

  // K DMA: instr c stages group w*4+c (rows w*16+c*4..+3);
  // lane l -> row +(l>>4), cols (l&15)*8..+7.
  const ushort* gK = qkv + (rowbase + w * 16 + (l >> 4)) * NQKV + 2048 + h * HDIM + (l & 15) * 8;
  auto issueK = [&](int kt, int buf) {
#pragma unroll
    for (int c = 0; c < 4; c++)
      gload_lds16(gK + (size_t)(kt * 64 + c * 4) * NQKV, &sK[buf][(w * 4 + c) * 528]);
  };
  // V: thread covers hd v_hd0..+7, t pair v_t0 (+32c)
  const int v_hd0 = (tid & 15) * 8;
  const int v_t0 = 2 * (tid >> 4);
  const ushort* gV = qkv + rowbase * NQKV + 4096 + h * HDIM + v_hd0;
  short8 vcur[4], vnxt[4];  // [0..1]=row t0 (c=0,1), [2..3]=row t0+1
  auto loadV = [&](int kt, short8* dst) {
#pragma unroll
    for (int c = 0; c < 2; c++) {
      const ushort* g = gV + (size_t)(kt * 64 + v_t0 + 32 * c) * NQKV;
      dst[c] = *(const short8*)g;
      dst[2 + c] = *(const short8*)(g + NQKV);
    }
  };

  ushort* myP = &sP[w * 16 * 72];
  const float scale = 0.08838834764831845f;  // 1/sqrt(128)

  auto attn_step = [&](bool diag, int buf) {
    floatx4 S[4];
#pragma unroll
    for (int j = 0; j < 4; j++) S[j] = zero;
#pragma unroll
    for (int s = 0; s < 4; s++)
#pragma unroll
      for (int j = 0; j < 4; j++) {
        int row = j * 16 + l16;
        short8 kf = *(const short8*)&sK[buf][(row >> 2) * 528 + (row & 3) * 128 + s * 32 + quad * 8];
        S[j] = __builtin_amdgcn_mfma_f32_16x16x32_bf16(qf[s], kf, S[j], 0, 0, 0);
      }
#pragma unroll
    for (int j = 0; j < 4; j++)
#pragma unroll
      for (int r = 0; r < 4; r++) {
        float v = S[j][r] * scale;
        if (diag && (j * 16 + l16 > w * 16 + quad * 4 + r)) v = NEG_BIG;
        S[j][r] = v;
      }
    float alpha[4];
#pragma unroll
    for (int r = 0; r < 4; r++) {
      float v = fmaxf(fmaxf(S[0][r], S[1][r]), fmaxf(S[2][r], S[3][r]));
      v = fmaxf(v, __shfl_xor(v, 1, 16));
      v = fmaxf(v, __shfl_xor(v, 2, 16));
      v = fmaxf(v, __shfl_xor(v, 4, 16));
      v = fmaxf(v, __shfl_xor(v, 8, 16));
      float mn = fmaxf(m_i[r], v);
      alpha[r] = __expf(m_i[r] - mn);
      m_i[r] = mn;
    }
#pragma unroll
    for (int j = 0; j < 4; j++)
#pragma unroll
      for (int r = 0; r < 4; r++) S[j][r] = __expf(S[j][r] - m_i[r]);
#pragma unroll
    for (int r = 0; r < 4; r++)
      l_i[r] = l_i[r] * alpha[r] + S[0][r] + S[1][r] + S[2][r] + S[3][r];
#pragma unroll
    for (int n = 0; n < 8; n++)
#pragma unroll
      for (int r = 0; r < 4; r++) o[n][r] *= alpha[r];
#pragma unroll
    for (int j = 0; j < 4; j++)
#pragma unroll
      for (int r = 0; r < 4; r++)
        myP[(quad * 4 + r) * 72 + j * 16 + l16] = f2bf(S[j][r]);
#pragma unroll
    for (int s = 0; s < 2; s++) {
      short8 pf = *(const short8*)&myP[l16 * 72 + s * 32 + quad * 8];
#pragma unroll
      for (int n = 0; n < 8; n++) {
        int hd = n * 16 + l16;
        short8 vf = *(const short8*)&sVt[hd * 72 + 8 * ((s * 4 + quad) ^ ((hd >> 3) & 7))];
        o[n] = __builtin_amdgcn_mfma_f32_16x16x32_bf16(pf, vf, o[n], 0, 0, 0);
      }
    }
  };

  issueK(0, 0);
  loadV(0, vcur);
  for (int kt = 0; kt <= qt; kt++) {
    const int buf = kt & 1;
    __syncthreads();   // drains this buf's K DMA (vmcnt0) + prev iter LDS reads
    // V^T staging (swizzled: write banks 2-way, reads b128 16B-aligned)
#pragma unroll
    for (int c = 0; c < 2; c++) {
      int tw = (v_t0 >> 1) + 16 * c;
#pragma unroll
      for (int j = 0; j < 8; j++) {
        int hd = v_hd0 + j;
        int phys = hd * 72 + 2 * (tw & 3) + 8 * ((tw >> 2) ^ ((hd >> 3) & 7));
        unsigned pv = ((unsigned)(ushort)vcur[c][j]) | (((unsigned)(ushort)vcur[2 + c][j]) << 16);
        *(unsigned*)&sVt[phys] = pv;
      }
    }
    __syncthreads();
    if (kt < qt) {     // prefetch next tile during this tile's compute
      issueK(kt + 1, buf ^ 1);
      loadV(kt + 1, vnxt);
    }
    attn_step(kt == qt, buf);
    if (kt < qt) {
#pragma unroll
      for (int c = 0; c < 4; c++) vcur[c] = vnxt[c];
    }
  }

  // epilogue: 1/l and store
#pragma unroll
  for (int r = 0; r < 4; r++) {
    float v = l_i[r];
    v += __shfl_xor(v, 1, 16);
    v += __shfl_xor(v, 2, 16);
    v += __shfl_xor(v, 4, 16);
    v += __shfl_xor(v, 8, 16);
    l_i[r] = 1.0f / v;
  }
#pragma unroll
  for (int n = 0; n < 8; n++) {
    int col = h * HDIM + n * 16 + l16;
#pragma unroll
    for (int r = 0; r < 4; r++) {
      int row = qt * 64 + w * 16 + quad * 4 + r;
      attn[(rowbase + row) * DMODEL + col] = f2bf(o[n][r] * l_i[r]);
    }
  }
}

extern "C" void kernel_launch(void* const* d_in, const int* in_sizes, int n_in,
                              void* d_out, int out_size, void* d_ws, size_t ws_size,
                              hipStream_t stream) {
  const float* xf    = (const float*)d_in[0];   // [4096, 2048] fp32
  const float* Wqkvf = (const float*)d_in[1];   // [2048, 6144] fp32
  const float* Woutf = (const float*)d_in[2];   // [2048, 2048] fp32
  float* outf = (float*)d_out;                  // [4096, 2048] fp32
  char* ws = (char*)d_ws;

  const size_t SZ_QKV  = (size_t)4096 * 6144 * 2;  // 50.33 MB
  const size_t SZ_ATTN = (size_t)4096 * 2048 * 2;  // 16.78 MB
  const size_t SZ_WQT  = (size_t)6144 * 2048 * 2;  // 25.17 MB

  ushort* xb = (ushort*)d_out;  // bf16 x in d_out scratch (dead before final write)
  cvt2d<<<8192, 256, 0, stream>>>(xf, xb, 4096, 2048, 2048);

  if (ws_size >= SZ_QKV + SZ_ATTN + SZ_WQT) {
    // Tier A: un-sliced QKV gemm (256^2 8-phase), attn in ws, final gemm to d_out.
    ushort* qkv   = (ushort*)ws;
    ushort* attnb = (ushort*)(ws + SZ_QKV);
    ushort* WT    = (ushort*)(ws + SZ_QKV + SZ_ATTN);
    cvt2dT<<<dim3(192, 64), dim3(32, 8), 0, stream>>>(Wqkvf, WT, 2048, 6144, NQKV);
    gemm_bt_256<ushort><<<dim3(16, 24), 512, 0, stream>>>(xb, WT, qkv, 4096, 6144, 2048, NQKV);
    flash_attn<<<dim3(32, 32), 256, 0, stream>>>(qkv, attnb);
    cvt2dT<<<dim3(64, 64), dim3(32, 8), 0, stream>>>(Woutf, WT, 2048, 2048, 2048);
    gemm_bt<float><<<dim3(32, 16), 256, 0, stream>>>(attnb, WT, outf, 4096, 2048, 2048, DMODEL);
  } else {
    // Tier B (ws >= 50.33 MB): sliced QKV, attn in d_out, memcpy back.
    ushort* qkv   = (ushort*)ws;
    float*  of    = (float*)ws;
    ushort* wbT   = (ushort*)d_out + (size_t)4096 * 2048;
    ushort* attnb = xb;
    for (int s = 0; s < 3; s++) {
      cvt2dT<<<dim3(64, 64), dim3(32, 8), 0, stream>>>(Wqkvf + s * 2048, wbT, 2048, 2048, NQKV);
      gemm_bt<ushort><<<dim3(32, 16), 256, 0, stream>>>(xb, wbT, qkv + s * 2048, 4096, 2048, 2048, NQKV);
    }
    flash_attn<<<dim3(32, 32), 256, 0, stream>>>(qkv, attnb);
    cvt2dT<<<dim3(64, 64), dim3(32, 8), 0, stream>>>(Woutf, wbT, 2048, 2048, 2048);
    gemm_bt<float><<<dim3(32, 16), 256, 0, stream>>>(attnb, wbT, of, 4096, 2048, 2048, DMODEL);
    hipMemcpyAsync(outf, of, (size_t)4096 * 2048 * 4, hipMemcpyDeviceToDevice, stream);
  }
}

// Round 2
// 399.910 us; speedup vs baseline: 1.0150x; 1.0150x over previous
//
#include <hip/hip_runtime.h>

// Causal self-attention. fp32 in/out, bf16 MFMA compute inside.
// R9: T2 swizzle added to the 256x256 8-phase QKV GEMM. R8's [256][32] K-half
// layout was an 8-way read conflict (bank set = (row&1)*16+quad*4: 16 lanes on
// 2 sets) -> 9.4M SQ_LDS_BANK_CONFLICT. Fix per rule #21: LDS stays LINEAR
// (global_load_lds dest), the 16B-granule permutation g ^= (row>>1)&3 is
// applied to the per-lane GLOBAL source on stage and to the read offset.
// Read bank set becomes (row&1)*4 + (quad^((row>>1)&3)): 16 lanes cover all
// 8 sets exactly twice -> 2-way (free, m136). Schedule/vmcnt unchanged.
// Flash attn + out-GEMM (m97 128^2) unchanged.
// MFMA 16x16x32 bf16 layouts (guide m89/m91):
//   A[m=lane&15][k=quad*8+j], B[k=quad*8+j][n=lane&15], C/D: row=quad*4+r, col=lane&15

typedef unsigned short ushort;
typedef __attribute__((ext_vector_type(8))) short short8;
typedef __attribute__((ext_vector_type(4))) float floatx4;

#define T_SEQ 2048
#define NQKV  6144
#define DMODEL 2048
#define HDIM  128
#define NEG_BIG (-3.0e38f)

#define WAITVM(n) asm volatile("s_waitcnt vmcnt(" #n ")" ::: "memory")
#define WAITLGKM0 asm volatile("s_waitcnt lgkmcnt(0)" ::: "memory")

__device__ __forceinline__ ushort f2bf(float f) {
  unsigned u = __float_as_uint(f);
  u += 0x7fffu + ((u >> 16) & 1u);   // RNE
  return (ushort)(u >> 16);
}
__device__ __forceinline__ void stout(ushort* p, float v) { *p = f2bf(v); }
__device__ __forceinline__ void stout(float* p, float v)  { *p = v; }

__device__ __forceinline__ void gload_lds16(const ushort* g, ushort* l) {
  __builtin_amdgcn_global_load_lds(
      (const __attribute__((address_space(1))) void*)g,
      (__attribute__((address_space(3))) void*)l,
      16, 0, 0);
}

// ---- fp32 [R x C] (row stride ld_in) -> dense bf16 [R x C] ----
__global__ void cvt2d(const float* __restrict__ in, ushort* __restrict__ out,
                      int R, int C, int ld_in) {
  int idx = blockIdx.x * blockDim.x + threadIdx.x;
  int c4 = C >> 2;
  if (idx >= R * c4) return;
  int r = idx / c4, c = (idx - r * c4) * 4;
  float4 v = *(const float4*)(in + (size_t)r * ld_in + c);
  ushort4 o;
  o.x = f2bf(v.x); o.y = f2bf(v.y); o.z = f2bf(v.z); o.w = f2bf(v.w);
  *(ushort4*)(out + (size_t)r * C + c) = o;
}

// ---- fp32 in[R][C] (row stride ld_in) -> bf16 out[C][R] dense ----
__global__ void cvt2dT(const float* __restrict__ in, ushort* __restrict__ out,
                       int R, int C, int ld_in) {
  __shared__ float tile[32][33];
  int c0 = blockIdx.x * 32, r0 = blockIdx.y * 32;
  int tx = threadIdx.x, ty = threadIdx.y;  // 32 x 8
#pragma unroll
  for (int q = 0; q < 4; q++)
    tile[ty + q * 8][tx] = in[(size_t)(r0 + ty + q * 8) * ld_in + c0 + tx];
  __syncthreads();
#pragma unroll
  for (int q = 0; q < 4; q++)
    out[(size_t)(c0 + ty + q * 8) * R + r0 + tx] = f2bf(tile[tx][ty + q * 8]);
}

// ---- C[M,N] = A[M,K] @ Bt[N,K]^T, bf16 in, OutT out (m97 structure) ----
template <typename OutT>
__global__ void gemm_bt(
    const ushort* __restrict__ A, const ushort* __restrict__ Bt,
    OutT* __restrict__ C, int M, int N, int K, int ldc) {
  __shared__ ushort sA[128 * 32];
  __shared__ ushort sB[128 * 32];
  const int tid = threadIdx.x;
  const int w = tid >> 6, l = tid & 63;
  const int quad = l >> 4, l16 = l & 15;
  const int row0 = blockIdx.x * 128, col0 = blockIdx.y * 128;
  const int wm = (w >> 1) * 64, wn = (w & 1) * 64;

  floatx4 acc[4][4];
  const floatx4 zero = {0.f, 0.f, 0.f, 0.f};
#pragma unroll
  for (int i = 0; i < 4; i++)
#pragma unroll
    for (int j = 0; j < 4; j++) acc[i][j] = zero;

  const int srow = w * 16 + (l >> 2);
  const int scol = (l & 3) * 8;
  const ushort* gA = A + (size_t)(row0 + srow) * K + scol;
  const ushort* gB = Bt + (size_t)(col0 + srow) * K + scol;
  ushort* lA = &sA[(w * 16) * 32];
  ushort* lB = &sB[(w * 16) * 32];

  for (int k0 = 0; k0 < K; k0 += 32) {
    __syncthreads();
    gload_lds16(gA + k0, lA);
    gload_lds16(gA + k0 + (size_t)64 * K, lA + 64 * 32);
    gload_lds16(gB + k0, lB);
    gload_lds16(gB + k0 + (size_t)64 * K, lB + 64 * 32);
    __syncthreads();
    short8 af[4], bfr[4];
#pragma unroll
    for (int i = 0; i < 4; i++)
      af[i] = *(const short8*)&sA[(wm + i * 16 + l16) * 32 + quad * 8];
#pragma unroll
    for (int j = 0; j < 4; j++)
      bfr[j] = *(const short8*)&sB[(wn + j * 16 + l16) * 32 + quad * 8];
#pragma unroll
    for (int i = 0; i < 4; i++)
#pragma unroll
      for (int j = 0; j < 4; j++)
        acc[i][j] = __builtin_amdgcn_mfma_f32_16x16x32_bf16(af[i], bfr[j], acc[i][j], 0, 0, 0);
  }

#pragma unroll
  for (int i = 0; i < 4; i++)
#pragma unroll
    for (int j = 0; j < 4; j++) {
      int r0 = row0 + wm + i * 16 + quad * 4;
      int c = col0 + wn + j * 16 + l16;
#pragma unroll
      for (int r = 0; r < 4; r++)
        stout(&C[(size_t)(r0 + r) * ldc + c], acc[i][j][r]);
    }
}

// ---- C[M,N] = A[M,K] @ Bt[N,K]^T, bf16 in, 256^2 8-phase pipeline ----
// 512 threads = 8 waves (2M x 4N); per-wave C = 128x64 (8 m-frags x 4 n-frags).
// LDS per operand: [2 buf][2 ks][256 rows][32 k] bf16 (64KB); total 128KB.
// T2 swizzle (rule #21, both-sides): 16B granule g at row r stored at
// physical granule g ^ ((r>>1)&3). LDS dest of global_load_lds stays linear;
// the permutation is applied to the per-lane GLOBAL source address on stage
// (lane l loads granule (l&3)^((l>>3)&3) of row l>>2) and to the read offset
// (quad ^ ((l16>>1)&3)). Read bank-set = (row&1)*4 + (quad^((row>>1)&3)):
// each of 8 sets hit exactly 2x per 16-lane group -> conflict-free.
// Per tile t (buf=t&1), 4 phases (ks,ch): P0=(0,0) P1=(0,1) P2=(1,0) P3=(1,1).
// Phase stages one 16KB unit (2 x global_load_lds dwordx4 per thread):
//   P0: t+1 A-ks1 (other buf)   P1: t+1 B-ks1 (other buf)
//   P2: t+2 A-ks0 (this buf; last reader was P1)   P3: t+2 B-ks0 (ditto)
// Boundary wait at P3: vmcnt(4) -> tile t+1 fully landed, 2 units in flight.
template <typename OutT>
__global__ __launch_bounds__(512, 2) void gemm_bt_256(
    const ushort* __restrict__ A, const ushort* __restrict__ Bt,
    OutT* __restrict__ C, int M, int N, int K, int ldc) {
  __shared__ ushort sA[2][2][256 * 32];
  __shared__ ushort sB[2][2][256 * 32];
  const int tid = threadIdx.x;
  const int wid = tid >> 6, l = tid & 63;
  const int quad = l >> 4, l16 = l & 15;
  const int wr = wid >> 2, wc = wid & 3;
  const int row0 = blockIdx.x * 256, col0 = blockIdx.y * 256;
  const int NT = K >> 6;

  floatx4 acc[8][4];
  const floatx4 zero = {0.f, 0.f, 0.f, 0.f};
#pragma unroll
  for (int i = 0; i < 8; i++)
#pragma unroll
    for (int j = 0; j < 4; j++) acc[i][j] = zero;

  // staging: wave wid covers rows [wid*32, wid*32+32); lane l -> row +(l>>2),
  // global k-granule (l&3)^((l>>3)&3) (inverse-swizzled source; LDS dest linear).
  const int sgr = ((l & 3) ^ ((l >> 3) & 3)) * 8;
  const ushort* gA = A + (size_t)(row0 + wid * 32 + (l >> 2)) * K + sgr;
  const ushort* gB = Bt + (size_t)(col0 + wid * 32 + (l >> 2)) * K + sgr;

  auto stageA = [&](int tt, int ks) {
    ushort* dst = &sA[tt & 1][ks][(wid * 32) * 32];
    const ushort* g = gA + (size_t)tt * 64 + ks * 32;
    gload_lds16(g, dst);
    gload_lds16(g + (size_t)16 * K, dst + 16 * 32);
  };
  auto stageB = [&](int tt, int ks) {
    ushort* dst = &sB[tt & 1][ks][(wid * 32) * 32];
    const ushort* g = gB + (size_t)tt * 64 + ks * 32;
    gload_lds16(g, dst);
    gload_lds16(g + (size_t)16 * K, dst + 16 * 32);
  };

  // read-side swizzled granule offset (row mod 16 == l16 for all frag reads)
  const int gsw = (quad ^ ((l16 >> 1) & 3)) * 8;

  // prologue: tile0 all 4 units + tile1 ks0 units -> vmcnt(4) leaves tile1's
  // 2 units in flight, tile0 fully landed.
  stageA(0, 0); stageB(0, 0); stageA(0, 1); stageB(0, 1);
  if (NT > 1) {
    stageA(1, 0); stageB(1, 0);
    WAITVM(4);
  } else {
    WAITVM(0);
  }
  __builtin_amdgcn_s_barrier();

#define PHASE(ks, ch, STAGE_STMT, VM_TAIL)                                    \
  {                                                                           \
    if ((ch) == 0) {                                                          \
      _Pragma("unroll")                                                       \
      for (int j = 0; j < 4; j++)                                             \
        bfr[j] = *(const short8*)&sB[buf][ks][(wc * 64 + j * 16 + l16) * 32 + gsw]; \
    }                                                                         \
    _Pragma("unroll")                                                         \
    for (int i = 0; i < 4; i++)                                               \
      af[i] = *(const short8*)&sA[buf][ks][(wr * 128 + ((ch) * 4 + i) * 16 + l16) * 32 + gsw]; \
    STAGE_STMT;                                                               \
    __builtin_amdgcn_s_barrier();                                             \
    WAITLGKM0;                                                                \
    __builtin_amdgcn_s_setprio(1);                                            \
    _Pragma("unroll")                                                         \
    for (int i = 0; i < 4; i++)                                               \
      _Pragma("unroll")                                                       \
      for (int j = 0; j < 4; j++)                                             \
        acc[(ch) * 4 + i][j] = __builtin_amdgcn_mfma_f32_16x16x32_bf16(       \
            af[i], bfr[j], acc[(ch) * 4 + i][j], 0, 0, 0);                    \
    __builtin_amdgcn_s_setprio(0);                                            \
    VM_TAIL;                                                                  \
    __builtin_amdgcn_s_barrier();                                             \
  }

  for (int t = 0; t < NT; ++t) {
    const int buf = t & 1;
    short8 af[4], bfr[4];
    PHASE(0, 0, if (t + 1 < NT) stageA(t + 1, 1), );
    PHASE(0, 1, if (t + 1 < NT) stageB(t + 1, 1), );
    PHASE(1, 0, if (t + 2 < NT) stageA(t + 2, 0), );
    PHASE(1, 1, if (t + 2 < NT) stageB(t + 2, 0),
          if (t < NT - 2) { WAITVM(4); } else if (t == NT - 2) { WAITVM(0); });
  }
#undef PHASE

#pragma unroll
  for (int mi = 0; mi < 8; mi++)
#pragma unroll
    for (int j = 0; j < 4; j++) {
      int r0 = row0 + wr * 128 + mi * 16 + quad * 4;
      int c = col0 + wc * 64 + j * 16 + l16;
#pragma unroll
      for (int r = 0; r < 4; r++)
        stout(&C[(size_t)(r0 + r) * ldc + c], acc[mi][j][r]);
    }
}

// ---- flash attention (causal): one 64-row q-tile per block; grid (bh, qtOrd) ----
// sK: 2 buffers, 16 groups each; group = 4 rows x 128 ushort + 16-ushort pad
// (528 ushort stride). DMA writes one group per instruction (1024B contig);
// the pad staggers groups by 8 banks -> K-fragment b128 reads are 4-way.
__global__ __launch_bounds__(256, 2) void flash_attn(
    const ushort* __restrict__ qkv, ushort* __restrict__ attn) {
  __shared__ ushort sK[2][16 * 528];
  __shared__ ushort sVt[128 * 72];   // swizzled [hd][t]
  __shared__ ushort sP[4 * 16 * 72]; // per-wave P, stride 72

  const int tid = threadIdx.x;
  const int w = tid >> 6, l = tid & 63;
  const int quad = l >> 4, l16 = l & 15;
  const int bh = blockIdx.x;            // bh-major: same-bh blocks share an XCD
  const int qt = 31 - (int)blockIdx.y;  // biggest blocks dispatch first
  const int b = bh >> 4, h = bh & 15;
  const size_t rowbase = (size_t)b * T_SEQ;

  short8 qf[4];
  {
    const ushort* qp = qkv + (rowbase + qt * 64 + w * 16 + l16) * NQKV + h * HDIM + quad * 8;
#pragma unroll
    for (int s = 0; s < 4; s++) qf[s] = *(const short8*)(qp + s * 32);
  }
  floatx4 o[8];
  const floatx4 zero = {0.f, 0.f, 0.f, 0.f};
#pragma unroll
  for (int n = 0; n < 8; n++) o[n] = zero;
  float m_i[4], l_i[4];
#pragma unroll
  for (int r = 0; r < 4; r++) { m_i[r] = NEG_BIG; l_i[r] = 0.f; }

  // K DMA: instr c stages group w*4+c (rows w*16+c*4..+3);
  // lane l -> row +(l>>4), cols (l&15)*8..+7.
  const ushort* gK = qkv + (rowbase + w * 16 + (l >> 4)) * NQKV + 2048 + h * HDIM + (l & 15) * 8;
  auto issueK = [&](int kt, int buf) {
#pragma unroll
    for (int c = 0; c < 4; c++)
      gload_lds16(gK + (size_t)(kt * 64 + c * 4) * NQKV, &sK[buf][(w * 4 + c) * 528]);
  };
  // V: thread covers hd v_hd0..+7, t pair v_t0 (+32c)
  const int v_hd0 = (tid & 15) * 8;
  const int v_t0 = 2 * (tid >> 4);
  const ushort* gV = qkv + rowbase * NQKV + 4096 + h * HDIM + v_hd0;
  short8 vcur[4], vnxt[4];  // [0..1]=row t0 (c=0,1), [2..3]=row t0+1
  auto loadV = [&](int kt, short8* dst) {
#pragma unroll
    for (int c = 0; c < 2; c++) {
      const ushort* g = gV + (size_t)(kt * 64 + v_t0 + 32 * c) * NQKV;
      dst[c] = *(const short8*)g;
      dst[2 + c] = *(const short8*)(g + NQKV);
    }
  };

  ushort* myP = &sP[w * 16 * 72];
  const float scale = 0.08838834764831845f;  // 1/sqrt(128)

  auto attn_step = [&](bool diag, int buf) {
    floatx4 S[4];
#pragma unroll
    for (int j = 0; j < 4; j++) S[j] = zero;
#pragma unroll
    for (int s = 0; s < 4; s++)
#pragma unroll
      for (int j = 0; j < 4; j++) {
        int row = j * 16 + l16;
        short8 kf = *(const short8*)&sK[buf][(row >> 2) * 528 + (row & 3) * 128 + s * 32 + quad * 8];
        S[j] = __builtin_amdgcn_mfma_f32_16x16x32_bf16(qf[s], kf, S[j], 0, 0, 0);
      }
#pragma unroll
    for (int j = 0; j < 4; j++)
#pragma unroll
      for (int r = 0; r < 4; r++) {
        float v = S[j][r] * scale;
        if (diag && (j * 16 + l16 > w * 16 + quad * 4 + r)) v = NEG_BIG;
        S[j][r] = v;
      }
    float alpha[4];
#pragma unroll
    for (int r = 0; r < 4; r++) {
      float v = fmaxf(fmaxf(S[0][r], S[1][r]), fmaxf(S[2][r], S[3][r]));
      v = fmaxf(v, __shfl_xor(v, 1, 16));
      v = fmaxf(v, __shfl_xor(v, 2, 16));
      v = fmaxf(v, __shfl_xor(v, 4, 16));
      v = fmaxf(v, __shfl_xor(v, 8, 16));
      float mn = fmaxf(m_i[r], v);
      alpha[r] = __expf(m_i[r] - mn);
      m_i[r] = mn;
    }
#pragma unroll
    for (int j = 0; j < 4; j++)
#pragma unroll
      for (int r = 0; r < 4; r++) S[j][r] = __expf(S[j][r] - m_i[r]);
#pragma unroll
    for (int r = 0; r < 4; r++)
      l_i[r] = l_i[r] * alpha[r] + S[0][r] + S[1][r] + S[2][r] + S[3][r];
#pragma unroll
    for (int n = 0; n < 8; n++)
#pragma unroll
      for (int r = 0; r < 4; r++) o[n][r] *= alpha[r];
#pragma unroll
    for (int j = 0; j < 4; j++)
#pragma unroll
      for (int r = 0; r < 4; r++)
        myP[(quad * 4 + r) * 72 + j * 16 + l16] = f2bf(S[j][r]);
#pragma unroll
    for (int s = 0; s < 2; s++) {
      short8 pf = *(const short8*)&myP[l16 * 72 + s * 32 + quad * 8];
#pragma unroll
      for (int n = 0; n < 8; n++) {
        int hd = n * 16 + l16;
        short8 vf = *(const short8*)&sVt[hd * 72 + 8 * ((s * 4 + quad) ^ ((hd >> 3) & 7))];
        o[n] = __builtin_amdgcn_mfma_f32_16x16x32_bf16(pf, vf, o[n], 0, 0, 0);
      }
    }
  };

  issueK(0, 0);
  loadV(0, vcur);
  for (int kt = 0; kt <= qt; kt++) {
    const int buf = kt & 1;
    __syncthreads();   // drains this buf's K DMA (vmcnt0) + prev iter LDS reads
    // V^T staging (swizzled: write banks 2-way, reads b128 16B-aligned)
#pragma unroll
    for (int c = 0; c < 2; c++) {
      int tw = (v_t0 >> 1) + 16 * c;
#pragma unroll
      for (int j = 0; j < 8; j++) {
        int hd = v_hd0 + j;
        int phys = hd * 72 + 2 * (tw & 3) + 8 * ((tw >> 2) ^ ((hd >> 3) & 7));
        unsigned pv = ((unsigned)(ushort)vcur[c][j]) | (((unsigned)(ushort)vcur[2 + c][j]) << 16);
        *(unsigned*)&sVt[phys] = pv;
      }
    }
    __syncthreads();
    if (kt < qt) {     // prefetch next tile during this tile's compute
      issueK(kt + 1, buf ^ 1);
      loadV(kt + 1, vnxt);
    }
    attn_step(kt == qt, buf);
    if (kt < qt) {
#pragma unroll
      for (int c = 0; c < 4; c++) vcur[c] = vnxt[c];
    }
  }

  // epilogue: 1/l and store
#pragma unroll
  for (int r = 0; r < 4; r++) {
    float v = l_i[r];
    v += __shfl_xor(v, 1, 16);
    v += __shfl_xor(v, 2, 16);
    v += __shfl_xor(v, 4, 16);
    v += __shfl_xor(v, 8, 16);
    l_i[r] = 1.0f / v;
  }
#pragma unroll
  for (int n = 0; n < 8; n++) {
    int col = h * HDIM + n * 16 + l16;
#pragma unroll
    for (int r = 0; r < 4; r++) {
      int row = qt * 64 + w * 16 + quad * 4 + r;
      attn[(rowbase + row) * DMODEL + col] = f2bf(o[n][r] * l_i[r]);
    }
  }
}

extern "C" void kernel_launch(void* const* d_in, const int* in_sizes, int n_in,
                              void* d_out, int out_size, void* d_ws, size_t ws_size,
                              hipStream_t stream) {
  const float* xf    = (const float*)d_in[0];   // [4096, 2048] fp32
  const float* Wqkvf = (const float*)d_in[1];   // [2048, 6144] fp32
  const float* Woutf = (const float*)d_in[2];   // [2048, 2048] fp32
  float* outf = (float*)d_out;                  // [4096, 2048] fp32
  char* ws = (char*)d_ws;

  const size_t SZ_QKV  = (size_t)4096 * 6144 * 2;  // 50.33 MB
  const size_t SZ_ATTN = (size_t)4096 * 2048 * 2;  // 16.78 MB
  const size_t SZ_WQT  = (size_t)6144 * 2048 * 2;  // 25.17 MB

  ushort* xb = (ushort*)d_out;  // bf16 x in d_out scratch (dead before final write)
  cvt2d<<<8192, 256, 0, stream>>>(xf, xb, 4096, 2048, 2048);

  if (ws_size >= SZ_QKV + SZ_ATTN + SZ_WQT) {
    // Tier A: un-sliced QKV gemm (256^2 8-phase), attn in ws, final gemm to d_out.
    ushort* qkv   = (ushort*)ws;
    ushort* attnb = (ushort*)(ws + SZ_QKV);
    ushort* WT    = (ushort*)(ws + SZ_QKV + SZ_ATTN);
    cvt2dT<<<dim3(192, 64), dim3(32, 8), 0, stream>>>(Wqkvf, WT, 2048, 6144, NQKV);
    gemm_bt_256<ushort><<<dim3(16, 24), 512, 0, stream>>>(xb, WT, qkv, 4096, 6144, 2048, NQKV);
    flash_attn<<<dim3(32, 32), 256, 0, stream>>>(qkv, attnb);
    cvt2dT<<<dim3(64, 64), dim3(32, 8), 0, stream>>>(Woutf, WT, 2048, 2048, 2048);
    gemm_bt<float><<<dim3(32, 16), 256, 0, stream>>>(attnb, WT, outf, 4096, 2048, 2048, DMODEL);
  } else {
    // Tier B (ws >= 50.33 MB): sliced QKV, attn in d_out, memcpy back.
    ushort* qkv   = (ushort*)ws;
    float*  of    = (float*)ws;
    ushort* wbT   = (ushort*)d_out + (size_t)4096 * 2048;
    ushort* attnb = xb;
    for (int s = 0; s < 3; s++) {
      cvt2dT<<<dim3(64, 64), dim3(32, 8), 0, stream>>>(Wqkvf + s * 2048, wbT, 2048, 2048, NQKV);
      gemm_bt<ushort><<<dim3(32, 16), 256, 0, stream>>>(xb, wbT, qkv + s * 2048, 4096, 2048, 2048, NQKV);
    }
    flash_attn<<<dim3(32, 32), 256, 0, stream>>>(qkv, attnb);
    cvt2dT<<<dim3(64, 64), dim3(32, 8), 0, stream>>>(Woutf, wbT, 2048, 2048, 2048);
    gemm_bt<float><<<dim3(32, 16), 256, 0, stream>>>(attnb, wbT, of, 4096, 2048, 2048, DMODEL);
    hipMemcpyAsync(outf, of, (size_t)4096 * 2048 * 4, hipMemcpyDeviceToDevice, stream);
  }
}